// Round 13
// baseline (459.361 us; speedup 1.0000x reference)
//
#include <hip/hip_runtime.h>

#define C_N   512
#define E_N   261632
#define CAP   768          // bucket capacity per receiver (max count ~590)

typedef _Float16 f16;
typedef _Float16 f16x8_t __attribute__((ext_vector_type(8)));
typedef float    f32x16_t __attribute__((ext_vector_type(16)));

// ---------------- K1: everything-prep (r5 exact) ----------------
// [0,64):   SA/RB MFMA GEMM w/ LDS-staged W1
// [64,192): W2 pack  [192,256): Wo1 pack  [256,384): Wo2 pack
// [384,448): Wo3 pack  [448]: zero cnt  [449]: zero agg
__global__ __launch_bounds__(256) void k_prep_all(
    const float* __restrict__ inputs, const float* __restrict__ W1,
    const float* __restrict__ b1, const float* __restrict__ W2,
    const float* __restrict__ Wo1, const float* __restrict__ Wo2, const float* __restrict__ Wo3,
    f16* __restrict__ SA, f16* __restrict__ RB, f16* __restrict__ W2p,
    f16* __restrict__ Wo1p, f16* __restrict__ Wo2p, f16* __restrict__ Wo3p,
    int* __restrict__ cnt, float* __restrict__ agg)
{
  __shared__ f16 wt[2][256][18];
  int bid = blockIdx.x;
  int tid = threadIdx.x;
  if (bid < 64) {
    int lane = tid & 63, w = tid >> 6;
    int hlf = lane >> 5, l31 = lane & 31;
    int br = bid & 7, bc = (bid >> 3) & 1, mi = bid >> 4;
    int t = mi >> 1, half = mi & 1;
    const float* Wsrc = W1 + (size_t)t * 512 * 512 + (size_t)half * 256 * 512;

    f32x16_t acc[2][2];
    #pragma unroll
    for (int rt = 0; rt < 2; rt++)
      #pragma unroll
      for (int ctl = 0; ctl < 2; ctl++)
        #pragma unroll
        for (int r = 0; r < 16; r++) acc[rt][ctl][r] = 0.f;

    #pragma unroll
    for (int i = 0; i < 4; i++) {
      int idx = tid + i * 256;
      int k = idx >> 6, n4 = idx & 63;
      float4 v = *(const float4*)&Wsrc[(size_t)k * 512 + bc * 256 + n4 * 4];
      wt[0][n4 * 4 + 0][k] = (f16)v.x;
      wt[0][n4 * 4 + 1][k] = (f16)v.y;
      wt[0][n4 * 4 + 2][k] = (f16)v.z;
      wt[0][n4 * 4 + 3][k] = (f16)v.w;
    }

    for (int kc = 0; kc < 16; kc++) {
      __syncthreads();
      if (kc + 1 < 16) {
        int b = (kc + 1) & 1;
        #pragma unroll
        for (int i = 0; i < 4; i++) {
          int idx = tid + i * 256;
          int k = idx >> 6, n4 = idx & 63;
          float4 v = *(const float4*)&Wsrc[(size_t)((kc + 1) * 16 + k) * 512 + bc * 256 + n4 * 4];
          wt[b][n4 * 4 + 0][k] = (f16)v.x;
          wt[b][n4 * 4 + 1][k] = (f16)v.y;
          wt[b][n4 * 4 + 2][k] = (f16)v.z;
          wt[b][n4 * 4 + 3][k] = (f16)v.w;
        }
      }
      f16x8_t af[2];
      #pragma unroll
      for (int rt = 0; rt < 2; rt++) {
        const float4* p = (const float4*)&inputs[(size_t)(br * 64 + rt * 32 + l31) * 256 + kc * 16 + hlf * 8];
        float4 u0 = p[0], u1 = p[1];
        af[rt] = (f16x8_t){(f16)u0.x, (f16)u0.y, (f16)u0.z, (f16)u0.w,
                           (f16)u1.x, (f16)u1.y, (f16)u1.z, (f16)u1.w};
      }
      int b = kc & 1;
      #pragma unroll
      for (int ctl = 0; ctl < 2; ctl++) {
        int n = (2 * w + ctl) * 32 + l31;
        f16x8_t bfr = *(const f16x8_t*)&wt[b][n][hlf * 8];
        #pragma unroll
        for (int rt = 0; rt < 2; rt++)
          acc[rt][ctl] = __builtin_amdgcn_mfma_f32_32x32x16_f16(af[rt], bfr, acc[rt][ctl], 0, 0, 0);
      }
    }
    f16* dst = (half == 0) ? SA : RB;
    #pragma unroll
    for (int ctl = 0; ctl < 2; ctl++) {
      int col = bc * 256 + (2 * w + ctl) * 32 + l31;
      float bias = (half == 1) ? b1[t * 512 + col] : 0.f;
      #pragma unroll
      for (int rt = 0; rt < 2; rt++)
        #pragma unroll
        for (int r = 0; r < 16; r++) {
          int row = br * 64 + rt * 32 + (r & 3) + 8 * (r >> 2) + 4 * hlf;
          dst[((size_t)(t * 512 + row)) * 512 + col] = (f16)(acc[rt][ctl][r] + bias);
        }
    }
  } else if (bid < 192) {
    int gid  = (bid - 64) * 256 + tid;
    int lane = gid & 63;
    int ct   = (gid >> 6) & 7;
    int kc   = (gid >> 9) & 31;
    int t    = gid >> 14;
    int n    = ct * 32 + (lane & 31);
    int k0   = kc * 16 + (lane >> 5) * 8;
    const float* src = W2 + (size_t)t * 512 * 256;
    f16x8_t v;
    #pragma unroll
    for (int j = 0; j < 8; j++) v[j] = (f16)src[(size_t)(k0 + j) * 256 + n];
    *(f16x8_t*)(W2p + (size_t)gid * 8) = v;
  } else if (bid < 256) {
    int gid  = (bid - 192) * 256 + tid;
    int lane = gid & 63;
    int ct   = (gid >> 6) & 15;
    int kc   = gid >> 10;
    int n    = ct * 32 + (lane & 31);
    int k0   = kc * 16 + (lane >> 5) * 8;
    f16x8_t v;
    #pragma unroll
    for (int j = 0; j < 8; j++) v[j] = (f16)Wo1[(size_t)(k0 + j) * 512 + n];
    *(f16x8_t*)(Wo1p + (size_t)gid * 8) = v;
  } else if (bid < 384) {
    int gid  = (bid - 256) * 256 + tid;
    int lane = gid & 63;
    int ct   = (gid >> 6) & 15;
    int kc   = gid >> 10;
    int n    = ct * 32 + (lane & 31);
    int k0   = kc * 16 + (lane >> 5) * 8;
    f16x8_t v;
    #pragma unroll
    for (int j = 0; j < 8; j++) v[j] = (f16)Wo2[(size_t)(k0 + j) * 512 + n];
    *(f16x8_t*)(Wo2p + (size_t)gid * 8) = v;
  } else if (bid < 448) {
    int gid  = (bid - 384) * 256 + tid;
    int lane = gid & 63;
    int ct   = (gid >> 6) & 7;
    int kc   = gid >> 9;
    int n    = ct * 32 + (lane & 31);
    int k0   = kc * 16 + (lane >> 5) * 8;
    f16x8_t v;
    #pragma unroll
    for (int j = 0; j < 8; j++) v[j] = (f16)Wo3[(size_t)(k0 + j) * 256 + n];
    *(f16x8_t*)(Wo3p + (size_t)gid * 8) = v;
  } else if (bid == 448) {
    for (int i = tid; i < 512 * 16; i += 256) cnt[i] = 0;
  } else {
    float4* a4 = (float4*)agg;
    for (int i = tid; i < 512 * 64; i += 256) a4[i] = make_float4(0.f, 0.f, 0.f, 0.f);
  }
}

// ---------------- K2: bucketed scatter (r5 exact) ----------------
__global__ __launch_bounds__(512) void k_scatter_d(const int* __restrict__ rec,
    const int* __restrict__ send, const float* __restrict__ rel,
    int* __restrict__ cnt, uint2* __restrict__ smeta)
{
  __shared__ int lh[512];
  __shared__ int lb[512];
  int b = blockIdx.x;
  int e0 = b * (E_N / 128);   // 2044 exactly
  lh[threadIdx.x] = 0;
  __syncthreads();
  for (int i = threadIdx.x; i < E_N / 128; i += 512)
    atomicAdd(&lh[rec[e0 + i]], 1);
  __syncthreads();
  {
    int c = lh[threadIdx.x];
    lb[threadIdx.x] = c ? atomicAdd(&cnt[threadIdx.x * 16], c) : 0;
    lh[threadIdx.x] = 0;
  }
  __syncthreads();
  for (int i = threadIdx.x; i < E_N / 128; i += 512) {
    int e = e0 + i;
    int r = rec[e];
    int p = r * CAP + lb[r] + atomicAdd(&lh[r], 1);
    f16 r0 = (f16)rel[2 * (size_t)e];
    f16 r1 = (f16)rel[2 * (size_t)e + 1];
    unsigned pk = ((unsigned)__builtin_bit_cast(unsigned short, r1) << 16)
                |  (unsigned)__builtin_bit_cast(unsigned short, r0);
    smeta[p] = make_uint2((unsigned)send[e], pk);
  }
}

// ---------------- K3: edge MLP — v10: BARRIER-FREE K-loop, zero-LDS A ----------------
// r13: the 32x32x16 A-fragment layout (lane l holds A[l&31][(l>>5)*8+0..7],
// 8 CONTIGUOUS k of one row) is exactly a per-lane 16B load from SA at row
// sends[rg*64+(l&31)]. So gather A-fragments DIRECTLY from global (L2-
// resident, 1MB), add RB via LDS broadcast, relu in-register — h1, all
// ds_writes, and every K-loop barrier are gone. Waves run independently:
// the lockstep phase wall (phase time = SUM of pipe times; falsified grafts
// r3/r5/r7/r12) is removed structurally. Cost: A L2-traffic x4 (cg dup),
// +16 VALU/kc — both overlap (m114). Barriers: 1 after staging, 1 before
// final aggL read.
__global__ __launch_bounds__(512, 4) void k_edges(
    const f16* __restrict__ SA, const f16* __restrict__ RB,
    const f16* __restrict__ W2p, const float* __restrict__ b2,
    const uint2* __restrict__ smeta, const int* __restrict__ cnt,
    float* __restrict__ agg)
{
  __shared__ f16   rbs[2][512];                // 2048 B
  __shared__ float b2s[2][256];                // 2048 B
  __shared__ float aggL[2][256];               // 2048 B
  __shared__ __align__(16) float relv[2][128]; // 1024 B
  __shared__ int   sends[128];                 // 512 B  -> ~7.7 KB LDS

  int c   = blockIdx.x;
  int ti  = blockIdx.y;
  int n_c = cnt[c * 16];
  if (ti * 128 >= n_c) return;               // empty tile -> whole block exits

  int tid  = threadIdx.x;
  int lane = tid & 63;
  int w    = tid >> 6;
  int hlf  = lane >> 5;
  int l31  = lane & 31;
  int rg   = w >> 2;        // row group: rows [rg*64, rg*64+64)
  int cg   = w & 3;         // col group: cols [cg*64, cg*64+64)

  if (tid < 128) {
    int t = tid >> 6, qq = tid & 63;
    *(f16x8_t*)&rbs[t][qq * 8] = *(const f16x8_t*)&RB[((size_t)(t * 512 + c)) * 512 + qq * 8];
  }
  ((float*)aggL)[tid] = 0.f;                 // 512 floats, 512 threads
  { int t = (tid >> 8) & 1, col = tid & 255; b2s[t][col] = b2[t * 256 + col]; }

  int s0 = c * CAP + ti * 128;
  int nv = n_c - ti * 128; if (nv > 128) nv = 128;   // valid edges this tile

  if (tid < 128) {
    if (tid < nv) {
      uint2 m = smeta[s0 + tid];
      sends[tid] = (int)m.x;
      relv[0][tid] = (float)__builtin_bit_cast(f16, (unsigned short)(m.y & 0xffffu));
      relv[1][tid] = (float)__builtin_bit_cast(f16, (unsigned short)(m.y >> 16));
    } else {
      sends[tid] = 0; relv[0][tid] = 0.f; relv[1][tid] = 0.f;
    }
  }
  __syncthreads();   // staging visible to all waves; NO more barriers until the end

  // per-lane A row indices for this wave's two 32-row tiles
  int srow0 = sends[rg * 64 + l31];
  int srow1 = sends[rg * 64 + 32 + l31];

  const f16x8_t* SAc = (const f16x8_t*)SA;
  const f16x8_t* Bp  = (const f16x8_t*)W2p;

  const f16 fz = (f16)0.f;
  const f16x8_t z8 = {fz, fz, fz, fz, fz, fz, fz, fz};

  f32x16_t acc[2][2];

  for (int p = 0; p < 8; p++) {
    int t  = p >> 2;          // edge type
    int ks = p & 3;           // K=128 slice within type

    if (ks == 0) {
      #pragma unroll
      for (int a = 0; a < 2; a++)
        #pragma unroll
        for (int b_ = 0; b_ < 2; b_++)
          #pragma unroll
          for (int r = 0; r < 16; r++) acc[a][b_][r] = 0.f;
    }

    // A chunk bases (f16x8 units): (t*512+row)*64 + ks*16 + kc*2 + hlf
    int abase0 = (t * 512 + srow0) * 64 + ks * 16 + hlf;
    int abase1 = (t * 512 + srow1) * 64 + ks * 16 + hlf;

    // B pointer for this wave's 2 col-tiles (ct = cg*2 + ctl), k-chunks ks*8..
    const f16x8_t* Bw = Bp + ((size_t)((t * 32 + ks * 8) * 8 + cg * 2) * 64 + lane);

    f16x8_t bb[2][2];
    bb[0][0] = Bw[0];    bb[0][1] = Bw[64];
    bb[1][0] = Bw[512];  bb[1][1] = Bw[512 + 64];

    f16x8_t ga0 = SAc[abase0];     // kc=0 gathers
    f16x8_t ga1 = SAc[abase1];

    #pragma unroll
    for (int kc = 0; kc < 8; kc++) {
      int qb = kc & 1;
      f16x8_t rbq = *(const f16x8_t*)&rbs[t][ks * 128 + kc * 16 + hlf * 8];  // broadcast
      f16x8_t af0 = __builtin_elementwise_max(ga0 + rbq, z8);   // relu(SA+RB) in-reg
      f16x8_t af1 = __builtin_elementwise_max(ga1 + rbq, z8);
      if (kc < 7) {                                             // 1-deep gather prefetch
        ga0 = SAc[abase0 + (kc + 1) * 2];
        ga1 = SAc[abase1 + (kc + 1) * 2];
      }
      acc[0][0] = __builtin_amdgcn_mfma_f32_32x32x16_f16(af0, bb[qb][0], acc[0][0], 0, 0, 0);
      acc[0][1] = __builtin_amdgcn_mfma_f32_32x32x16_f16(af0, bb[qb][1], acc[0][1], 0, 0, 0);
      acc[1][0] = __builtin_amdgcn_mfma_f32_32x32x16_f16(af1, bb[qb][0], acc[1][0], 0, 0, 0);
      acc[1][1] = __builtin_amdgcn_mfma_f32_32x32x16_f16(af1, bb[qb][1], acc[1][1], 0, 0, 0);
      if (kc + 2 < 8) {
        bb[qb][0] = Bw[(kc + 2) * 512];
        bb[qb][1] = Bw[(kc + 2) * 512 + 64];
      }
    }

    if (ks == 3) {
      #pragma unroll
      for (int ctl = 0; ctl < 2; ctl++) {
        int col = (cg * 2 + ctl) * 32 + l31;
        float b2c = b2s[t][col];
        float csum = 0.f;
        #pragma unroll
        for (int rt = 0; rt < 2; rt++) {
          int rbase = rg * 64 + rt * 32 + 4 * hlf;
          #pragma unroll
          for (int grp = 0; grp < 4; grp++) {
            float4 rv = *(const float4*)&relv[t][rbase + 8 * grp];  // broadcast
            float v0 = fmaxf(acc[rt][ctl][grp * 4 + 0] + b2c, 0.f);
            float v1 = fmaxf(acc[rt][ctl][grp * 4 + 1] + b2c, 0.f);
            float v2 = fmaxf(acc[rt][ctl][grp * 4 + 2] + b2c, 0.f);
            float v3 = fmaxf(acc[rt][ctl][grp * 4 + 3] + b2c, 0.f);
            csum += v0 * rv.x + v1 * rv.y + v2 * rv.z + v3 * rv.w;
          }
        }
        csum += __shfl_xor(csum, 32, 64);
        if (hlf == 0) aggL[rg][col] += csum;    // (rg,col) owned by exactly one wave
      }
    }
  }

  __syncthreads();   // all waves' aggL writes -> final read

  if (tid < 256) atomicAdd(&agg[(size_t)c * 256 + tid], aggL[0][tid] + aggL[1][tid]);
}

// ---------------- K4: fused output MLP (r11: 1024 thr / 16 waves) ----------------
#define HOS 520

__global__ __launch_bounds__(1024, 4) void k_omlp(const float* __restrict__ agg,
    const f16* __restrict__ Wo1p, const float* __restrict__ bo1,
    const f16* __restrict__ Wo2p, const float* __restrict__ bo2,
    const f16* __restrict__ Wo3p, const float* __restrict__ bo3,
    float* __restrict__ out)
{
  __shared__ f16 hL1[32 * HOS];   // 33280 B
  __shared__ f16 hL2[32 * HOS];   // 33280 B
  int tid = threadIdx.x, lane = tid & 63, w = tid >> 6;   // 16 waves
  int hlf = lane >> 5, l31 = lane & 31;
  int br = blockIdx.x;            // 32 rows per block

  // layer 1: rows 32, cols 512, K=256 (16 waves x 1 ct)
  {
    f32x16_t acc;
    #pragma unroll
    for (int r = 0; r < 16; r++) acc[r] = 0.f;
    for (int kc = 0; kc < 16; kc++) {
      const float4* p = (const float4*)&agg[(size_t)(br * 32 + l31) * 256 + kc * 16 + hlf * 8];
      float4 u0 = p[0], u1 = p[1];
      f16x8_t af = (f16x8_t){(f16)u0.x, (f16)u0.y, (f16)u0.z, (f16)u0.w,
                             (f16)u1.x, (f16)u1.y, (f16)u1.z, (f16)u1.w};
      f16x8_t bfr = *(const f16x8_t*)&Wo1p[((size_t)(kc * 16 + w) * 64 + lane) * 8];
      acc = __builtin_amdgcn_mfma_f32_32x32x16_f16(af, bfr, acc, 0, 0, 0);
    }
    int col = w * 32 + l31;
    float bias = bo1[col];
    #pragma unroll
    for (int r = 0; r < 16; r++) {
      int row = (r & 3) + 8 * (r >> 2) + 4 * hlf;
      hL1[row * HOS + col] = (f16)fmaxf(acc[r] + bias, 0.f);
    }
  }
  __syncthreads();

  // layer 2: rows 32, cols 512, K=512 (16 waves x 1 ct)
  {
    f32x16_t acc;
    #pragma unroll
    for (int r = 0; r < 16; r++) acc[r] = 0.f;
    for (int kc = 0; kc < 32; kc++) {
      f16x8_t af  = *(const f16x8_t*)&hL1[l31 * HOS + kc * 16 + hlf * 8];
      f16x8_t bfr = *(const f16x8_t*)&Wo2p[((size_t)(kc * 16 + w) * 64 + lane) * 8];
      acc = __builtin_amdgcn_mfma_f32_32x32x16_f16(af, bfr, acc, 0, 0, 0);
    }
    int col = w * 32 + l31;
    float bias = bo2[col];
    #pragma unroll
    for (int r = 0; r < 16; r++) {
      int row = (r & 3) + 8 * (r >> 2) + 4 * hlf;
      hL2[row * HOS + col] = (f16)fmaxf(acc[r] + bias, 0.f);
    }
  }
  __syncthreads();

  // layer 3: rows 32, cols 256, K=512 (waves 0-7 x 1 ct; no barrier after)
  if (w < 8) {
    f32x16_t acc;
    #pragma unroll
    for (int r = 0; r < 16; r++) acc[r] = 0.f;
    for (int kc = 0; kc < 32; kc++) {
      f16x8_t af  = *(const f16x8_t*)&hL2[l31 * HOS + kc * 16 + hlf * 8];
      f16x8_t bfr = *(const f16x8_t*)&Wo3p[((size_t)(kc * 8 + w) * 64 + lane) * 8];
      acc = __builtin_amdgcn_mfma_f32_32x32x16_f16(af, bfr, acc, 0, 0, 0);
    }
    int col = w * 32 + l31;
    float bias = bo3[col];
    #pragma unroll
    for (int r = 0; r < 16; r++) {
      int row = br * 32 + (r & 3) + 8 * (r >> 2) + 4 * hlf;
      out[(size_t)row * 256 + col] = acc[r] + bias;
    }
  }
}

// ---------------- launcher (r11 exact) ----------------
extern "C" void kernel_launch(void* const* d_in, const int* in_sizes, int n_in,
                              void* d_out, int out_size, void* d_ws, size_t ws_size,
                              hipStream_t stream)
{
  (void)in_sizes; (void)n_in; (void)out_size; (void)ws_size;
  const float* inputs = (const float*)d_in[0];
  const float* rel    = (const float*)d_in[1];
  const float* W1     = (const float*)d_in[2];
  const float* b1     = (const float*)d_in[3];
  const float* W2     = (const float*)d_in[4];
  const float* b2     = (const float*)d_in[5];
  const float* Wo1    = (const float*)d_in[6];
  const float* bo1    = (const float*)d_in[7];
  const float* Wo2    = (const float*)d_in[8];
  const float* bo2    = (const float*)d_in[9];
  const float* Wo3    = (const float*)d_in[10];
  const float* bo3    = (const float*)d_in[11];
  const int* send_idx = (const int*)d_in[12];
  const int* rec_idx  = (const int*)d_in[13];
  float* out = (float*)d_out;

  char* ws = (char*)d_ws;
  f16*    SA    = (f16*)   (ws);                   // 1 MB
  f16*    RB    = (f16*)   (ws + (1024u << 10));   // 1 MB
  f16*    W2p   = (f16*)   (ws + (2048u << 10));   // 512 KB
  float*  agg   = (float*) (ws + (2560u << 10));   // 512 KB
  int*    cnt   = (int*)   (ws + (3072u << 10));   // 32 KB
  f16*    Wo1p  = (f16*)   (ws + (3136u << 10));   // 256 KB
  f16*    Wo2p  = (f16*)   (ws + (3392u << 10));   // 512 KB
  f16*    Wo3p  = (f16*)   (ws + (3904u << 10));   // 256 KB
  uint2*  smeta = (uint2*) (ws + (4160u << 10));   // 3 MB -> total ~7.2 MB

  k_prep_all <<<dim3(450),    dim3(256),  0, stream>>>(inputs, W1, b1, W2, Wo1, Wo2, Wo3,
                                                       SA, RB, W2p, Wo1p, Wo2p, Wo3p, cnt, agg);
  k_scatter_d<<<dim3(128),    dim3(512),  0, stream>>>(rec_idx, send_idx, rel, cnt, smeta);
  k_edges    <<<dim3(512, 5), dim3(512),  0, stream>>>(SA, RB, W2p, b2, smeta, cnt, agg);
  k_omlp     <<<dim3(16),     dim3(1024), 0, stream>>>(agg, Wo1p, bo1, Wo2p, bo2, Wo3p, bo3, out);
}

// Round 14
// 286.859 us; speedup vs baseline: 1.6013x; 1.6013x over previous
//
#include <hip/hip_runtime.h>

#define C_N   512
#define E_N   261632
#define CAP   768          // bucket capacity per receiver (max count ~590)

typedef _Float16 f16;
typedef _Float16 f16x8_t __attribute__((ext_vector_type(8)));
typedef float    f32x16_t __attribute__((ext_vector_type(16)));

// ---------------- K1: everything-prep (r5 exact) ----------------
// [0,64):   SA/RB MFMA GEMM w/ LDS-staged W1
// [64,192): W2 pack  [192,256): Wo1 pack  [256,384): Wo2 pack
// [384,448): Wo3 pack  [448]: zero cnt  [449]: zero agg
__global__ __launch_bounds__(256) void k_prep_all(
    const float* __restrict__ inputs, const float* __restrict__ W1,
    const float* __restrict__ b1, const float* __restrict__ W2,
    const float* __restrict__ Wo1, const float* __restrict__ Wo2, const float* __restrict__ Wo3,
    f16* __restrict__ SA, f16* __restrict__ RB, f16* __restrict__ W2p,
    f16* __restrict__ Wo1p, f16* __restrict__ Wo2p, f16* __restrict__ Wo3p,
    int* __restrict__ cnt, float* __restrict__ agg)
{
  __shared__ f16 wt[2][256][18];
  int bid = blockIdx.x;
  int tid = threadIdx.x;
  if (bid < 64) {
    int lane = tid & 63, w = tid >> 6;
    int hlf = lane >> 5, l31 = lane & 31;
    int br = bid & 7, bc = (bid >> 3) & 1, mi = bid >> 4;
    int t = mi >> 1, half = mi & 1;
    const float* Wsrc = W1 + (size_t)t * 512 * 512 + (size_t)half * 256 * 512;

    f32x16_t acc[2][2];
    #pragma unroll
    for (int rt = 0; rt < 2; rt++)
      #pragma unroll
      for (int ctl = 0; ctl < 2; ctl++)
        #pragma unroll
        for (int r = 0; r < 16; r++) acc[rt][ctl][r] = 0.f;

    #pragma unroll
    for (int i = 0; i < 4; i++) {
      int idx = tid + i * 256;
      int k = idx >> 6, n4 = idx & 63;
      float4 v = *(const float4*)&Wsrc[(size_t)k * 512 + bc * 256 + n4 * 4];
      wt[0][n4 * 4 + 0][k] = (f16)v.x;
      wt[0][n4 * 4 + 1][k] = (f16)v.y;
      wt[0][n4 * 4 + 2][k] = (f16)v.z;
      wt[0][n4 * 4 + 3][k] = (f16)v.w;
    }

    for (int kc = 0; kc < 16; kc++) {
      __syncthreads();
      if (kc + 1 < 16) {
        int b = (kc + 1) & 1;
        #pragma unroll
        for (int i = 0; i < 4; i++) {
          int idx = tid + i * 256;
          int k = idx >> 6, n4 = idx & 63;
          float4 v = *(const float4*)&Wsrc[(size_t)((kc + 1) * 16 + k) * 512 + bc * 256 + n4 * 4];
          wt[b][n4 * 4 + 0][k] = (f16)v.x;
          wt[b][n4 * 4 + 1][k] = (f16)v.y;
          wt[b][n4 * 4 + 2][k] = (f16)v.z;
          wt[b][n4 * 4 + 3][k] = (f16)v.w;
        }
      }
      f16x8_t af[2];
      #pragma unroll
      for (int rt = 0; rt < 2; rt++) {
        const float4* p = (const float4*)&inputs[(size_t)(br * 64 + rt * 32 + l31) * 256 + kc * 16 + hlf * 8];
        float4 u0 = p[0], u1 = p[1];
        af[rt] = (f16x8_t){(f16)u0.x, (f16)u0.y, (f16)u0.z, (f16)u0.w,
                           (f16)u1.x, (f16)u1.y, (f16)u1.z, (f16)u1.w};
      }
      int b = kc & 1;
      #pragma unroll
      for (int ctl = 0; ctl < 2; ctl++) {
        int n = (2 * w + ctl) * 32 + l31;
        f16x8_t bfr = *(const f16x8_t*)&wt[b][n][hlf * 8];
        #pragma unroll
        for (int rt = 0; rt < 2; rt++)
          acc[rt][ctl] = __builtin_amdgcn_mfma_f32_32x32x16_f16(af[rt], bfr, acc[rt][ctl], 0, 0, 0);
      }
    }
    f16* dst = (half == 0) ? SA : RB;
    #pragma unroll
    for (int ctl = 0; ctl < 2; ctl++) {
      int col = bc * 256 + (2 * w + ctl) * 32 + l31;
      float bias = (half == 1) ? b1[t * 512 + col] : 0.f;
      #pragma unroll
      for (int rt = 0; rt < 2; rt++)
        #pragma unroll
        for (int r = 0; r < 16; r++) {
          int row = br * 64 + rt * 32 + (r & 3) + 8 * (r >> 2) + 4 * hlf;
          dst[((size_t)(t * 512 + row)) * 512 + col] = (f16)(acc[rt][ctl][r] + bias);
        }
    }
  } else if (bid < 192) {
    int gid  = (bid - 64) * 256 + tid;
    int lane = gid & 63;
    int ct   = (gid >> 6) & 7;
    int kc   = (gid >> 9) & 31;
    int t    = gid >> 14;
    int n    = ct * 32 + (lane & 31);
    int k0   = kc * 16 + (lane >> 5) * 8;
    const float* src = W2 + (size_t)t * 512 * 256;
    f16x8_t v;
    #pragma unroll
    for (int j = 0; j < 8; j++) v[j] = (f16)src[(size_t)(k0 + j) * 256 + n];
    *(f16x8_t*)(W2p + (size_t)gid * 8) = v;
  } else if (bid < 256) {
    int gid  = (bid - 192) * 256 + tid;
    int lane = gid & 63;
    int ct   = (gid >> 6) & 15;
    int kc   = gid >> 10;
    int n    = ct * 32 + (lane & 31);
    int k0   = kc * 16 + (lane >> 5) * 8;
    f16x8_t v;
    #pragma unroll
    for (int j = 0; j < 8; j++) v[j] = (f16)Wo1[(size_t)(k0 + j) * 512 + n];
    *(f16x8_t*)(Wo1p + (size_t)gid * 8) = v;
  } else if (bid < 384) {
    int gid  = (bid - 256) * 256 + tid;
    int lane = gid & 63;
    int ct   = (gid >> 6) & 15;
    int kc   = gid >> 10;
    int n    = ct * 32 + (lane & 31);
    int k0   = kc * 16 + (lane >> 5) * 8;
    f16x8_t v;
    #pragma unroll
    for (int j = 0; j < 8; j++) v[j] = (f16)Wo2[(size_t)(k0 + j) * 512 + n];
    *(f16x8_t*)(Wo2p + (size_t)gid * 8) = v;
  } else if (bid < 448) {
    int gid  = (bid - 384) * 256 + tid;
    int lane = gid & 63;
    int ct   = (gid >> 6) & 7;
    int kc   = gid >> 9;
    int n    = ct * 32 + (lane & 31);
    int k0   = kc * 16 + (lane >> 5) * 8;
    f16x8_t v;
    #pragma unroll
    for (int j = 0; j < 8; j++) v[j] = (f16)Wo3[(size_t)(k0 + j) * 256 + n];
    *(f16x8_t*)(Wo3p + (size_t)gid * 8) = v;
  } else if (bid == 448) {
    for (int i = tid; i < 512 * 16; i += 256) cnt[i] = 0;
  } else {
    float4* a4 = (float4*)agg;
    for (int i = tid; i < 512 * 64; i += 256) a4[i] = make_float4(0.f, 0.f, 0.f, 0.f);
  }
}

// ---------------- K2: bucketed scatter (r5 exact) ----------------
__global__ __launch_bounds__(512) void k_scatter_d(const int* __restrict__ rec,
    const int* __restrict__ send, const float* __restrict__ rel,
    int* __restrict__ cnt, uint2* __restrict__ smeta)
{
  __shared__ int lh[512];
  __shared__ int lb[512];
  int b = blockIdx.x;
  int e0 = b * (E_N / 128);   // 2044 exactly
  lh[threadIdx.x] = 0;
  __syncthreads();
  for (int i = threadIdx.x; i < E_N / 128; i += 512)
    atomicAdd(&lh[rec[e0 + i]], 1);
  __syncthreads();
  {
    int c = lh[threadIdx.x];
    lb[threadIdx.x] = c ? atomicAdd(&cnt[threadIdx.x * 16], c) : 0;
    lh[threadIdx.x] = 0;
  }
  __syncthreads();
  for (int i = threadIdx.x; i < E_N / 128; i += 512) {
    int e = e0 + i;
    int r = rec[e];
    int p = r * CAP + lb[r] + atomicAdd(&lh[r], 1);
    f16 r0 = (f16)rel[2 * (size_t)e];
    f16 r1 = (f16)rel[2 * (size_t)e + 1];
    unsigned pk = ((unsigned)__builtin_bit_cast(unsigned short, r1) << 16)
                |  (unsigned)__builtin_bit_cast(unsigned short, r0);
    smeta[p] = make_uint2((unsigned)send[e], pk);
  }
}

// ---------------- K3: edge MLP (r12 + wave-uniform tail skip) ----------------
// r14: r13's zero-LDS gather falsified (scattered 4x A-traffic saturated the
// TA/L2 request path: 376us, MfmaUtil 17.7%). Revert to r12 (best: 297.46us
// total) + ONE safe addition: wave-uniform `rgLive = rg*64 < nv` guard around
// the B-loads + MFMA cluster — tail tiles with nv<=64 let rg=1 waves skip all
// MFMA/B-traffic. Build/barriers/epilogue untouched (acc zeroed, relv=0 keeps
// pad rows inert); single uniform branch, no code dup -> no r2-style spill.
#define H1S 136   // stride 272 B = 68 dw ≡ 4 (mod 32) -> conflict-free b128 pattern

__global__ __launch_bounds__(512, 4) void k_edges(
    const f16* __restrict__ SA, const f16* __restrict__ RB,
    const f16* __restrict__ W2p, const float* __restrict__ b2,
    const uint2* __restrict__ smeta, const int* __restrict__ cnt,
    float* __restrict__ agg)
{
  __shared__ f16   h1[2][128][H1S];            // 69632 B
  __shared__ f16   rbs[2][512];                // 2048 B
  __shared__ float b2s[2][256];                // 2048 B
  __shared__ float aggL[2][256];               // 2048 B
  __shared__ __align__(16) float relv[2][128]; // 1024 B
  __shared__ int   sends[128];                 // 512 B  -> 77312 B, 2 blocks/CU

  int c   = blockIdx.x;
  int ti  = blockIdx.y;
  int n_c = cnt[c * 16];
  if (ti * 128 >= n_c) return;               // empty tile -> whole block exits

  int tid  = threadIdx.x;
  int lane = tid & 63;
  int w    = tid >> 6;
  int hlf  = lane >> 5;
  int l31  = lane & 31;
  int q4   = tid & 15;      // build: 16B chunk within 128-f16 slice
  int rb0  = tid >> 4;      // build: base row [0,32)
  int rg   = w >> 2;        // row group: rows [rg*64, rg*64+64)
  int cg   = w & 3;         // col group: cols [cg*64, cg*64+64)

  if (tid < 128) {
    int t = tid >> 6, qq = tid & 63;
    *(f16x8_t*)&rbs[t][qq * 8] = *(const f16x8_t*)&RB[((size_t)(t * 512 + c)) * 512 + qq * 8];
  }
  ((float*)aggL)[tid] = 0.f;                 // 512 floats, 512 threads
  { int t = (tid >> 8) & 1, col = tid & 255; b2s[t][col] = b2[t * 256 + col]; }

  int s0 = c * CAP + ti * 128;
  int nv = n_c - ti * 128; if (nv > 128) nv = 128;   // valid edges this tile

  if (tid < 128) {
    if (tid < nv) {
      uint2 m = smeta[s0 + tid];
      sends[tid] = (int)m.x;
      relv[0][tid] = (float)__builtin_bit_cast(f16, (unsigned short)(m.y & 0xffffu));
      relv[1][tid] = (float)__builtin_bit_cast(f16, (unsigned short)(m.y >> 16));
    } else {
      sends[tid] = 0; relv[0][tid] = 0.f; relv[1][tid] = 0.f;
    }
  }
  __syncthreads();

  bool rgLive = (rg * 64 < nv);   // wave-uniform: rg=1 waves idle on nv<=64 tails

  const f16x8_t* SAc = (const f16x8_t*)SA;
  const f16x8_t* Bp  = (const f16x8_t*)W2p;

  const f16 fz = (f16)0.f;
  const f16x8_t z8 = {fz, fz, fz, fz, fz, fz, fz, fz};

  // per-thread gather voffsets in f16x8 units (rows rb0+32j, chunk q4)
  int voff[4];
  #pragma unroll
  for (int j = 0; j < 4; j++)
    voff[j] = sends[rb0 + 32 * j] * 64 + q4;

  f16x8_t g[4];

  // prologue: gather + build phase 0 (t=0, ks=0) into h1[0]
  #pragma unroll
  for (int j = 0; j < 4; j++) g[j] = SAc[voff[j]];
  {
    f16x8_t rbq = *(const f16x8_t*)&rbs[0][q4 * 8];
    #pragma unroll
    for (int j = 0; j < 4; j++) {
      f16x8_t sv = g[j] + rbq;                          // v_pk_add_f16 x4
      sv = __builtin_elementwise_max(sv, z8);           // v_pk_max_f16 x4
      *(f16x8_t*)&h1[0][rb0 + 32 * j][q4 * 8] = sv;
    }
  }

  f32x16_t acc[2][2];

  for (int p = 0; p < 8; p++) {
    int t  = p >> 2;          // edge type
    int ks = p & 3;           // K=128 slice within type
    int pb = p & 1;           // h1 buffer parity
    __syncthreads();          // h1[pb] ready; previous-parity readers done

    // prefetch next phase's gathers (consumed by build at end of this iter)
    if (p < 7) {
      int off = ((p + 1) >> 2) * 32768 + ((p + 1) & 3) * 16;
      #pragma unroll
      for (int j = 0; j < 4; j++) g[j] = SAc[voff[j] + off];
    }

    if (ks == 0) {
      #pragma unroll
      for (int a = 0; a < 2; a++)
        #pragma unroll
        for (int b_ = 0; b_ < 2; b_++)
          #pragma unroll
          for (int r = 0; r < 16; r++) acc[a][b_][r] = 0.f;
    }

    if (rgLive) {
      // B pointer for this wave's 2 col-tiles (ct = cg*2 + ctl), k-chunks ks*8..
      const f16x8_t* Bw = Bp + ((size_t)((t * 32 + ks * 8) * 8 + cg * 2) * 64 + lane);

      f16x8_t bb[2][2];
      bb[0][0] = Bw[0];    bb[0][1] = Bw[64];
      bb[1][0] = Bw[512];  bb[1][1] = Bw[512 + 64];

      const f16* h1b = &h1[pb][0][0];
      int a0 = (rg * 64 + l31) * H1S + hlf * 8;
      __builtin_amdgcn_s_setprio(1);
      #pragma unroll
      for (int kc = 0; kc < 8; kc++) {
        int qb = kc & 1;
        f16x8_t af0 = *(const f16x8_t*)&h1b[a0 + kc * 16];
        f16x8_t af1 = *(const f16x8_t*)&h1b[a0 + 32 * H1S + kc * 16];
        acc[0][0] = __builtin_amdgcn_mfma_f32_32x32x16_f16(af0, bb[qb][0], acc[0][0], 0, 0, 0);
        acc[0][1] = __builtin_amdgcn_mfma_f32_32x32x16_f16(af0, bb[qb][1], acc[0][1], 0, 0, 0);
        acc[1][0] = __builtin_amdgcn_mfma_f32_32x32x16_f16(af1, bb[qb][0], acc[1][0], 0, 0, 0);
        acc[1][1] = __builtin_amdgcn_mfma_f32_32x32x16_f16(af1, bb[qb][1], acc[1][1], 0, 0, 0);
        if (kc + 2 < 8) {
          bb[qb][0] = Bw[(kc + 2) * 512];
          bb[qb][1] = Bw[(kc + 2) * 512 + 64];
        }
      }
      __builtin_amdgcn_s_setprio(0);
    }

    if (ks == 3) {
      #pragma unroll
      for (int ctl = 0; ctl < 2; ctl++) {
        int col = (cg * 2 + ctl) * 32 + l31;
        float b2c = b2s[t][col];
        float csum = 0.f;
        #pragma unroll
        for (int rt = 0; rt < 2; rt++) {
          int rbase = rg * 64 + rt * 32 + 4 * hlf;
          #pragma unroll
          for (int grp = 0; grp < 4; grp++) {
            float4 rv = *(const float4*)&relv[t][rbase + 8 * grp];  // broadcast
            float v0 = fmaxf(acc[rt][ctl][grp * 4 + 0] + b2c, 0.f);
            float v1 = fmaxf(acc[rt][ctl][grp * 4 + 1] + b2c, 0.f);
            float v2 = fmaxf(acc[rt][ctl][grp * 4 + 2] + b2c, 0.f);
            float v3 = fmaxf(acc[rt][ctl][grp * 4 + 3] + b2c, 0.f);
            csum += v0 * rv.x + v1 * rv.y + v2 * rv.z + v3 * rv.w;
          }
        }
        csum += __shfl_xor(csum, 32, 64);
        if (hlf == 0) aggL[rg][col] += csum;    // (rg,col) owned by exactly one wave
      }
    }

    // build next phase into the OTHER buffer (overlaps other waves' MFMA)
    if (p < 7) {
      int tn = (p + 1) >> 2, ksn = (p + 1) & 3;
      f16x8_t rbq = *(const f16x8_t*)&rbs[tn][ksn * 128 + q4 * 8];
      #pragma unroll
      for (int j = 0; j < 4; j++) {
        f16x8_t sv = g[j] + rbq;
        sv = __builtin_elementwise_max(sv, z8);
        *(f16x8_t*)&h1[pb ^ 1][rb0 + 32 * j][q4 * 8] = sv;
      }
    }
  }

  __syncthreads();   // phase-7 epilogue aggL writes (waves 4-7) -> final read (waves 0-3)

  if (tid < 256) atomicAdd(&agg[(size_t)c * 256 + tid], aggL[0][tid] + aggL[1][tid]);
}

// ---------------- K4: fused output MLP (r11: 1024 thr / 16 waves) ----------------
#define HOS 520

__global__ __launch_bounds__(1024, 4) void k_omlp(const float* __restrict__ agg,
    const f16* __restrict__ Wo1p, const float* __restrict__ bo1,
    const f16* __restrict__ Wo2p, const float* __restrict__ bo2,
    const f16* __restrict__ Wo3p, const float* __restrict__ bo3,
    float* __restrict__ out)
{
  __shared__ f16 hL1[32 * HOS];   // 33280 B
  __shared__ f16 hL2[32 * HOS];   // 33280 B
  int tid = threadIdx.x, lane = tid & 63, w = tid >> 6;   // 16 waves
  int hlf = lane >> 5, l31 = lane & 31;
  int br = blockIdx.x;            // 32 rows per block

  // layer 1: rows 32, cols 512, K=256 (16 waves x 1 ct)
  {
    f32x16_t acc;
    #pragma unroll
    for (int r = 0; r < 16; r++) acc[r] = 0.f;
    for (int kc = 0; kc < 16; kc++) {
      const float4* p = (const float4*)&agg[(size_t)(br * 32 + l31) * 256 + kc * 16 + hlf * 8];
      float4 u0 = p[0], u1 = p[1];
      f16x8_t af = (f16x8_t){(f16)u0.x, (f16)u0.y, (f16)u0.z, (f16)u0.w,
                             (f16)u1.x, (f16)u1.y, (f16)u1.z, (f16)u1.w};
      f16x8_t bfr = *(const f16x8_t*)&Wo1p[((size_t)(kc * 16 + w) * 64 + lane) * 8];
      acc = __builtin_amdgcn_mfma_f32_32x32x16_f16(af, bfr, acc, 0, 0, 0);
    }
    int col = w * 32 + l31;
    float bias = bo1[col];
    #pragma unroll
    for (int r = 0; r < 16; r++) {
      int row = (r & 3) + 8 * (r >> 2) + 4 * hlf;
      hL1[row * HOS + col] = (f16)fmaxf(acc[r] + bias, 0.f);
    }
  }
  __syncthreads();

  // layer 2: rows 32, cols 512, K=512 (16 waves x 1 ct)
  {
    f32x16_t acc;
    #pragma unroll
    for (int r = 0; r < 16; r++) acc[r] = 0.f;
    for (int kc = 0; kc < 32; kc++) {
      f16x8_t af  = *(const f16x8_t*)&hL1[l31 * HOS + kc * 16 + hlf * 8];
      f16x8_t bfr = *(const f16x8_t*)&Wo2p[((size_t)(kc * 16 + w) * 64 + lane) * 8];
      acc = __builtin_amdgcn_mfma_f32_32x32x16_f16(af, bfr, acc, 0, 0, 0);
    }
    int col = w * 32 + l31;
    float bias = bo2[col];
    #pragma unroll
    for (int r = 0; r < 16; r++) {
      int row = (r & 3) + 8 * (r >> 2) + 4 * hlf;
      hL2[row * HOS + col] = (f16)fmaxf(acc[r] + bias, 0.f);
    }
  }
  __syncthreads();

  // layer 3: rows 32, cols 256, K=512 (waves 0-7 x 1 ct; no barrier after)
  if (w < 8) {
    f32x16_t acc;
    #pragma unroll
    for (int r = 0; r < 16; r++) acc[r] = 0.f;
    for (int kc = 0; kc < 32; kc++) {
      f16x8_t af  = *(const f16x8_t*)&hL2[l31 * HOS + kc * 16 + hlf * 8];
      f16x8_t bfr = *(const f16x8_t*)&Wo3p[((size_t)(kc * 8 + w) * 64 + lane) * 8];
      acc = __builtin_amdgcn_mfma_f32_32x32x16_f16(af, bfr, acc, 0, 0, 0);
    }
    int col = w * 32 + l31;
    float bias = bo3[col];
    #pragma unroll
    for (int r = 0; r < 16; r++) {
      int row = br * 32 + (r & 3) + 8 * (r >> 2) + 4 * hlf;
      out[(size_t)row * 256 + col] = acc[r] + bias;
    }
  }
}

// ---------------- launcher (r12 exact) ----------------
extern "C" void kernel_launch(void* const* d_in, const int* in_sizes, int n_in,
                              void* d_out, int out_size, void* d_ws, size_t ws_size,
                              hipStream_t stream)
{
  (void)in_sizes; (void)n_in; (void)out_size; (void)ws_size;
  const float* inputs = (const float*)d_in[0];
  const float* rel    = (const float*)d_in[1];
  const float* W1     = (const float*)d_in[2];
  const float* b1     = (const float*)d_in[3];
  const float* W2     = (const float*)d_in[4];
  const float* b2     = (const float*)d_in[5];
  const float* Wo1    = (const float*)d_in[6];
  const float* bo1    = (const float*)d_in[7];
  const float* Wo2    = (const float*)d_in[8];
  const float* bo2    = (const float*)d_in[9];
  const float* Wo3    = (const float*)d_in[10];
  const float* bo3    = (const float*)d_in[11];
  const int* send_idx = (const int*)d_in[12];
  const int* rec_idx  = (const int*)d_in[13];
  float* out = (float*)d_out;

  char* ws = (char*)d_ws;
  f16*    SA    = (f16*)   (ws);                   // 1 MB
  f16*    RB    = (f16*)   (ws + (1024u << 10));   // 1 MB
  f16*    W2p   = (f16*)   (ws + (2048u << 10));   // 512 KB
  float*  agg   = (float*) (ws + (2560u << 10));   // 512 KB
  int*    cnt   = (int*)   (ws + (3072u << 10));   // 32 KB
  f16*    Wo1p  = (f16*)   (ws + (3136u << 10));   // 256 KB
  f16*    Wo2p  = (f16*)   (ws + (3392u << 10));   // 512 KB
  f16*    Wo3p  = (f16*)   (ws + (3904u << 10));   // 256 KB
  uint2*  smeta = (uint2*) (ws + (4160u << 10));   // 3 MB -> total ~7.2 MB

  k_prep_all <<<dim3(450),    dim3(256),  0, stream>>>(inputs, W1, b1, W2, Wo1, Wo2, Wo3,
                                                       SA, RB, W2p, Wo1p, Wo2p, Wo3p, cnt, agg);
  k_scatter_d<<<dim3(128),    dim3(512),  0, stream>>>(rec_idx, send_idx, rel, cnt, smeta);
  k_edges    <<<dim3(512, 5), dim3(512),  0, stream>>>(SA, RB, W2p, b2, smeta, cnt, agg);
  k_omlp     <<<dim3(16),     dim3(1024), 0, stream>>>(agg, Wo1p, bo1, Wo2p, bo2, Wo3p, bo3, out);
}